// Round 1
// baseline (522.165 us; speedup 1.0000x reference)
//
#include <hip/hip_runtime.h>
#include <stdint.h>

typedef __bf16 bf16_t;
typedef __bf16 bf16x8 __attribute__((ext_vector_type(8)));
typedef float  f32x4  __attribute__((ext_vector_type(4)));

#define GLD_LDS(gp, lp) __builtin_amdgcn_global_load_lds( \
    (const __attribute__((address_space(1))) void*)(gp),  \
    (__attribute__((address_space(3))) void*)(lp), 16, 0, 0)

// ---------------------------------------------------------------------------
// dtype probe: flag=1 if inputs are bf16, 0 if fp32.
// ---------------------------------------------------------------------------
__global__ void probe_kernel(const unsigned int* __restrict__ w, int* __restrict__ flag)
{
    const int lane = threadIdx.x;   // 64 threads
    bool ok = true;
#pragma unroll
    for (int i = 0; i < 4; ++i) {
        unsigned x = w[lane * 4 + i];
        unsigned lo = x & 0xffffu, hi = x >> 16;
        ok = ok && (lo <= 0x3F80u) && (hi <= 0x3F80u);
    }
    unsigned long long m = __ballot(ok);
    if (lane == 0) *flag = (m == ~0ULL) ? 1 : 0;
}

// ---------------------------------------------------------------------------
// GEMM-BT mainloop: acc[128x128] = A[128xK] * B[128xK]^T   (bf16, fp32 acc)
// BK=64; slot permutation slot=c^(row&7) -> 2-way banks (free, m136).
// ---------------------------------------------------------------------------
__device__ __forceinline__ void gemm_mainloop(const bf16_t* __restrict__ Ag,
                                              const bf16_t* __restrict__ Bg,
                                              int K, bf16_t* Abuf, bf16_t* Bbuf,
                                              f32x4 acc[4][4])
{
    const int t    = threadIdx.x;
    const int wave = t >> 6;
    const int lane = t & 63;
    const int srow = (wave << 5) + (lane >> 3);
    const int sc   = ((lane & 7) ^ (lane >> 3)) << 3;   // swizzled chunk (elems)
    const bf16_t* aP = Ag + (size_t)srow * K + sc;
    const bf16_t* bP = Bg + (size_t)srow * K + sc;
    const size_t rskip = (size_t)8 * K;                 // 8 rows per instr
    bf16_t* aL = Abuf + (wave << 11);
    bf16_t* bL = Bbuf + (wave << 11);
    const int wm   = (wave & 1) << 6;
    const int wn   = (wave >> 1) << 6;
    const int lrow = lane & 15;
    const int quad = lane >> 4;
    const int g    = lrow & 7;
    const int so[2] = { (quad ^ g) << 3, ((4 | quad) ^ g) << 3 };

#pragma unroll
    for (int i = 0; i < 4; ++i)
#pragma unroll
        for (int j = 0; j < 4; ++j)
#pragma unroll
            for (int r = 0; r < 4; ++r) acc[i][j][r] = 0.0f;

    for (int kk = 0; kk < K; kk += 64) {
#pragma unroll
        for (int p = 0; p < 4; ++p) {
            GLD_LDS(aP + p * rskip, aL + (p << 9));
            GLD_LDS(bP + p * rskip, bL + (p << 9));
        }
        aP += 64; bP += 64;
        __syncthreads();

#pragma unroll
        for (int s = 0; s < 2; ++s) {
            bf16x8 af[4], bfv[4];
#pragma unroll
            for (int i = 0; i < 4; ++i) {
                af[i]  = *(const bf16x8*)(Abuf + ((wm + (i << 4) + lrow) << 6) + so[s]);
                bfv[i] = *(const bf16x8*)(Bbuf + ((wn + (i << 4) + lrow) << 6) + so[s]);
            }
#pragma unroll
            for (int i = 0; i < 4; ++i)
#pragma unroll
                for (int j = 0; j < 4; ++j)
                    acc[i][j] = __builtin_amdgcn_mfma_f32_16x16x32_bf16(af[i], bfv[j], acc[i][j], 0, 0, 0);
        }
        __syncthreads();
    }
}

// ---------------------------------------------------------------------------
// bmm: z[b,n,d] = sum_m adj[b,n,m]*xT[b,d,m] + xadd[b*N+n,d]  (bf16 out)
// Flat grid 1024 with XCD-aware decode: xcd=id&7; n0 innermost so the 4
// blocks sharing an adj row-tile are adjacent on one XCD's L2; each XCD
// owns 4 whole batches -> adj fetched from HBM once.
// ---------------------------------------------------------------------------
__global__ __launch_bounds__(256) void bmm_kernel(const void* __restrict__ adj_in,
                                                  const bf16_t* __restrict__ adj_ws,
                                                  const bf16_t* __restrict__ xT,
                                                  const void* __restrict__ xadd,
                                                  int xadd_bf16,
                                                  const int* __restrict__ flag,
                                                  bf16_t* __restrict__ zout)
{
    __shared__ __align__(16) bf16_t Abuf[8192];
    __shared__ __align__(16) bf16_t Bbuf[8192];
    const int is_bf = *flag;
    const bf16_t* adj = is_bf ? (const bf16_t*)adj_in : adj_ws;
    const int id   = blockIdx.x;
    const int xcd  = id & 7;
    const int slot = id >> 3;                // 0..127 per XCD
    const int n0   = (slot & 3) << 7;        // fastest: 4 n0 share adj tile
    const int m0   = ((slot >> 2) & 7) << 7; // 8 m0 tiles
    const int b    = (xcd << 2) | (slot >> 5); // 4 batches per XCD
    const bf16_t* Ag = adj + (size_t)b * 1048576 + (size_t)m0 * 1024;
    const bf16_t* Bg = xT  + (size_t)b * 524288  + (size_t)n0 * 1024;
    f32x4 acc[4][4];
    gemm_mainloop(Ag, Bg, 1024, Abuf, Bbuf, acc);

    const int lane = threadIdx.x & 63;
    const int wave = threadIdx.x >> 6;
    const int wm = (wave & 1) << 6, wn = (wave >> 1) << 6;
    const int lrow = lane & 15, quad = lane >> 4;
    const int xf32 = (!xadd_bf16) && (!is_bf);
    const size_t rowbase = (size_t)b * 1024 + m0;
#pragma unroll
    for (int i = 0; i < 4; ++i)
#pragma unroll
        for (int j = 0; j < 4; ++j)
#pragma unroll
            for (int r = 0; r < 4; ++r) {
                int row = wm + (i << 4) + (quad << 2) + r;
                int col = n0 + wn + (j << 4) + lrow;
                size_t idx = (rowbase + row) * 512 + col;
                float xa = xf32 ? ((const float*)xadd)[idx]
                                : (float)((const bf16_t*)xadd)[idx];
                zout[idx] = (bf16_t)(acc[i][j][r] + xa);
            }
}

// ---------------------------------------------------------------------------
// wgemm: y[n,j] = relu((sum_d z[n,d]*W[j,d] + 2*bias[j]) / (rowsum[n]+1))
// always bf16 out. grid (256,4)
// ---------------------------------------------------------------------------
__global__ __launch_bounds__(256) void wgemm_kernel(const bf16_t* __restrict__ z,
                                                    const bf16_t* __restrict__ W,
                                                    const float* __restrict__ bias,
                                                    const float* __restrict__ rowsum,
                                                    bf16_t* __restrict__ out)
{
    __shared__ __align__(16) bf16_t Abuf[8192];
    __shared__ __align__(16) bf16_t Bbuf[8192];
    const int m0 = blockIdx.x * 128;
    const int n0 = blockIdx.y * 128;
    const bf16_t* Ag = z + (size_t)m0 * 512;
    const bf16_t* Bg = W + (size_t)n0 * 512;
    f32x4 acc[4][4];
    gemm_mainloop(Ag, Bg, 512, Abuf, Bbuf, acc);

    const int lane = threadIdx.x & 63;
    const int wave = threadIdx.x >> 6;
    const int wm = (wave & 1) << 6, wn = (wave >> 1) << 6;
    const int lrow = lane & 15, quad = lane >> 4;
    float bi[4];
#pragma unroll
    for (int j = 0; j < 4; ++j) bi[j] = 2.0f * bias[n0 + wn + (j << 4) + lrow];
#pragma unroll
    for (int i = 0; i < 4; ++i)
#pragma unroll
        for (int r = 0; r < 4; ++r) {
            int row = m0 + wm + (i << 4) + (quad << 2) + r;
            float inv_dn = 1.0f / (rowsum[row] + 1.0f);
#pragma unroll
            for (int j = 0; j < 4; ++j) {
                int col = n0 + wn + (j << 4) + lrow;
                float v = fmaxf((acc[i][j][r] + bi[j]) * inv_dn, 0.0f);
                out[(size_t)row * 512 + col] = (bf16_t)v;
            }
        }
}

// ---------------------------------------------------------------------------
// transpose: in[b*N+n, d] -> out[b, d, n] (bf16). grid (16,8,32)
// ---------------------------------------------------------------------------
__global__ __launch_bounds__(256) void transpose_kernel(const void* __restrict__ in,
                                                        bf16_t* __restrict__ out,
                                                        const int* __restrict__ flag,
                                                        int force_bf16)
{
    __shared__ float tile[64][65];
    const int f32 = (!force_bf16) && (*flag == 0);
    const int b  = blockIdx.z;
    const int n0 = blockIdx.x * 64;
    const int d0 = blockIdx.y * 64;
    const int t  = threadIdx.x;
    const size_t base = ((size_t)b * 1024 + n0) * 512 + d0;
#pragma unroll
    for (int pass = 0; pass < 2; ++pass) {
        int r = pass * 32 + (t >> 3);
        int c = (t & 7) << 3;
        size_t off = base + (size_t)r * 512 + c;
        if (f32) {
            const float4* p = (const float4*)((const float*)in + off);
            float4 a = p[0], q = p[1];
            tile[r][c+0]=a.x; tile[r][c+1]=a.y; tile[r][c+2]=a.z; tile[r][c+3]=a.w;
            tile[r][c+4]=q.x; tile[r][c+5]=q.y; tile[r][c+6]=q.z; tile[r][c+7]=q.w;
        } else {
            bf16x8 v = *(const bf16x8*)((const bf16_t*)in + off);
#pragma unroll
            for (int k = 0; k < 8; ++k) tile[r][c + k] = (float)v[k];
        }
    }
    __syncthreads();
    bf16_t* dst = out + ((size_t)b * 512 + d0) * 1024 + n0;
#pragma unroll
    for (int pass = 0; pass < 2; ++pass) {
        int d = pass * 32 + (t >> 3);
        int c = (t & 7) << 3;
        bf16x8 v;
#pragma unroll
        for (int k = 0; k < 8; ++k) v[k] = (bf16_t)tile[c + k][d];
        *(bf16x8*)(dst + (size_t)d * 1024 + c) = v;
    }
}

// ---------------------------------------------------------------------------
// adjrow: rowsum + canonicalize adj->bf16 (store skipped when already bf16).
// ---------------------------------------------------------------------------
__global__ __launch_bounds__(256) void adjrow_kernel(const void* __restrict__ adj,
                                                     const int* __restrict__ flag,
                                                     bf16_t* __restrict__ adj_b,
                                                     float* __restrict__ rowsum)
{
    const int row  = blockIdx.x * 4 + (threadIdx.x >> 6);
    const int lane = threadIdx.x & 63;
    const int f32  = (*flag == 0);
    const size_t base = (size_t)row * 1024 + lane * 16;
    float v[16];
    if (f32) {
        const float4* p = (const float4*)((const float*)adj + base);
#pragma unroll
        for (int i = 0; i < 4; ++i) {
            float4 q = p[i];
            v[i*4+0]=q.x; v[i*4+1]=q.y; v[i*4+2]=q.z; v[i*4+3]=q.w;
        }
    } else {
        const bf16x8* p = (const bf16x8*)((const bf16_t*)adj + base);
        bf16x8 q0 = p[0], q1 = p[1];
#pragma unroll
        for (int k = 0; k < 8; ++k) { v[k] = (float)q0[k]; v[8+k] = (float)q1[k]; }
    }
    float s = 0.0f;
#pragma unroll
    for (int k = 0; k < 16; ++k) s += v[k];
    if (f32) {
        bf16x8 o0, o1;
#pragma unroll
        for (int k = 0; k < 8; ++k) { o0[k] = (bf16_t)v[k]; o1[k] = (bf16_t)v[8+k]; }
        *(bf16x8*)(adj_b + base)     = o0;
        *(bf16x8*)(adj_b + base + 8) = o1;
    }
#pragma unroll
    for (int off = 32; off > 0; off >>= 1) s += __shfl_down(s, off);
    if (lane == 0) rowsum[row] = s;
}

__global__ __launch_bounds__(256) void colsum_kernel(const void* __restrict__ adj_in,
                                                     const bf16_t* __restrict__ adj_ws,
                                                     const int* __restrict__ flag,
                                                     float* __restrict__ colsum)
{
    const bf16_t* a = (*flag) ? (const bf16_t*)adj_in : adj_ws;
    const int b = blockIdx.y;
    const int c = blockIdx.x * 256 + threadIdx.x;
    const int r0 = blockIdx.z * 256;
    const bf16_t* p = a + (size_t)b * 1048576 + (size_t)r0 * 1024 + c;
    float s = 0.0f;
#pragma unroll 8
    for (int r = 0; r < 256; ++r) s += (float)p[(size_t)r * 1024];
    atomicAdd(&colsum[b * 1024 + c], s);
}

__global__ __launch_bounds__(256) void mask_kernel(const float* __restrict__ rowsum,
                                                   const float* __restrict__ colsum,
                                                   void* __restrict__ out,
                                                   const int* __restrict__ flag)
{
    const int i = blockIdx.x * 256 + threadIdx.x;
    float m = (rowsum[i] + colsum[i] == 0.0f) ? 1.0f : 0.0f;
    if (*flag) ((bf16_t*)out)[16777216 + i] = (bf16_t)m;
    else       ((float*)out)[16777216 + i]  = m;
}

// canonicalize W0,W1 -> bf16; biases + ln params -> fp32; zero colsum.
// grid 2184 x 256 = 559,104 threads.
__global__ __launch_bounds__(256) void canon_small(const void* __restrict__ W0,
                                                   const void* __restrict__ W1,
                                                   const void* __restrict__ b0,
                                                   const void* __restrict__ b1,
                                                   const void* __restrict__ g,
                                                   const void* __restrict__ bt,
                                                   const int* __restrict__ flag,
                                                   bf16_t* __restrict__ W0ws,
                                                   bf16_t* __restrict__ W1ws,
                                                   float* __restrict__ par,
                                                   float* __restrict__ colsum)
{
    const int idx = blockIdx.x * 256 + threadIdx.x;
    const int f32 = (*flag == 0);
#define RD(p, i) (f32 ? ((const float*)(p))[i] : (float)((const bf16_t*)(p))[i])
    if      (idx < 262144) W0ws[idx]          = (bf16_t)RD(W0, idx);
    else if (idx < 524288) W1ws[idx - 262144] = (bf16_t)RD(W1, idx - 262144);
    else if (idx < 524800) par[idx - 524288]  = RD(b0, idx - 524288);
    else if (idx < 525312) par[idx - 524288]  = RD(b1, idx - 524800);
    else if (idx < 525824) par[idx - 524288]  = RD(g,  idx - 525312);
    else if (idx < 526336) par[idx - 524288]  = RD(bt, idx - 525824);
    else if (idx < 559104) colsum[idx - 526336] = 0.0f;
#undef RD
}

// ---------------------------------------------------------------------------
// LayerNorm rows of 512 (bf16 in, flagged dtype out). One wave/row.
// ---------------------------------------------------------------------------
__global__ __launch_bounds__(256) void ln_kernel(const bf16_t* __restrict__ x,
                                                 const float* __restrict__ g,
                                                 const float* __restrict__ bb,
                                                 void* __restrict__ out,
                                                 const int* __restrict__ flag)
{
    const int row  = blockIdx.x * 4 + (threadIdx.x >> 6);
    const int lane = threadIdx.x & 63;
    bf16x8 xv = *(const bf16x8*)(x + (size_t)row * 512 + lane * 8);
    float vv[8], s = 0.0f, ss = 0.0f;
#pragma unroll
    for (int k = 0; k < 8; ++k) { vv[k] = (float)xv[k]; s += vv[k]; ss += vv[k] * vv[k]; }
#pragma unroll
    for (int off = 32; off > 0; off >>= 1) { s += __shfl_down(s, off); ss += __shfl_down(ss, off); }
    s = __shfl(s, 0); ss = __shfl(ss, 0);
    const float mu   = s * (1.0f / 512.0f);
    const float var  = ss * (1.0f / 512.0f) - mu * mu;
    const float rstd = rsqrtf(var + 1e-5f);
    float o[8];
#pragma unroll
    for (int k = 0; k < 8; ++k)
        o[k] = (vv[k] - mu) * rstd * g[lane * 8 + k] + bb[lane * 8 + k];
    const size_t obase = (size_t)row * 512 + lane * 8;
    if (*flag) {
        bf16x8 ob;
#pragma unroll
        for (int k = 0; k < 8; ++k) ob[k] = (bf16_t)o[k];
        *(bf16x8*)((bf16_t*)out + obase) = ob;
    } else {
        float4 o0 = {o[0], o[1], o[2], o[3]}, o1 = {o[4], o[5], o[6], o[7]};
        *(float4*)((float*)out + obase)     = o0;
        *(float4*)((float*)out + obase + 4) = o1;
    }
}

// ---------------------------------------------------------------------------
extern "C" void kernel_launch(void* const* d_in, const int* in_sizes, int n_in,
                              void* d_out, int out_size, void* d_ws, size_t ws_size,
                              hipStream_t stream)
{
    const void* adj  = d_in[0];
    const void* x0   = d_in[1];
    const void* W0w  = d_in[3];
    const void* W0b  = d_in[4];
    const void* W1w  = d_in[5];
    const void* W1b  = d_in[6];
    const void* lng  = d_in[7];
    const void* lnb  = d_in[8];

    char* ws = (char*)d_ws;
    bf16_t* adj_ws = (bf16_t*)ws;                   // 64 MiB (fp32-input path only)
    bf16_t* x2     = (bf16_t*)ws;                   // aliases adj_ws after adj dead
    bf16_t* z_buf  = (bf16_t*)(ws + 67108864);
    bf16_t* x1     = (bf16_t*)(ws + 100663296);
    bf16_t* W0ws   = (bf16_t*)(ws + 134217728);
    bf16_t* W1ws   = (bf16_t*)(ws + 134742016);
    float*  par    = (float*)(ws + 135266304);
    float*  rowsum = (float*)(ws + 135274496);
    float*  colsum = (float*)(ws + 135405568);
    int*    flag   = (int*)(ws + 135536640);

    bf16_t* xT = (bf16_t*)d_out;   // d_out head doubles as xT scratch (dead before LN)

    probe_kernel<<<1, 64, 0, stream>>>((const unsigned int*)adj, flag);
    canon_small<<<2184, 256, 0, stream>>>(W0w, W1w, W0b, W1b, lng, lnb, flag,
                                          W0ws, W1ws, par, colsum);
    adjrow_kernel<<<8192, 256, 0, stream>>>(adj, flag, adj_ws, rowsum);
    colsum_kernel<<<dim3(4, 32, 4), 256, 0, stream>>>(adj, adj_ws, flag, colsum);
    mask_kernel<<<128, 256, 0, stream>>>(rowsum, colsum, d_out, flag);

    // layer 1
    transpose_kernel<<<dim3(16, 8, 32), 256, 0, stream>>>(x0, xT, flag, 0);
    bmm_kernel<<<1024, 256, 0, stream>>>(adj, adj_ws, xT, x0, 0, flag, z_buf);
    wgemm_kernel<<<dim3(256, 4), 256, 0, stream>>>(z_buf, W0ws, par, rowsum, x1);

    // layer 2
    transpose_kernel<<<dim3(16, 8, 32), 256, 0, stream>>>(x1, xT, flag, 1);
    bmm_kernel<<<1024, 256, 0, stream>>>(adj, adj_ws, xT, x1, 1, flag, z_buf);
    wgemm_kernel<<<dim3(256, 4), 256, 0, stream>>>(z_buf, W1ws, par + 512, rowsum, x2);

    // final layer norm -> d_out head
    ln_kernel<<<8192, 256, 0, stream>>>(x2, par + 1024, par + 1536, d_out, flag);
}

// Round 3
// 492.874 us; speedup vs baseline: 1.0594x; 1.0594x over previous
//
#include <hip/hip_runtime.h>
#include <stdint.h>

typedef __bf16 bf16_t;
typedef __bf16 bf16x8 __attribute__((ext_vector_type(8)));
typedef float  f32x4  __attribute__((ext_vector_type(4)));

#define GLD_LDS(gp, lp) __builtin_amdgcn_global_load_lds( \
    (const __attribute__((address_space(1))) void*)(gp),  \
    (__attribute__((address_space(3))) void*)(lp), 16, 0, 0)

// ---------------------------------------------------------------------------
// dtype probe: flag=1 if inputs are bf16, 0 if fp32.
// ---------------------------------------------------------------------------
__global__ void probe_kernel(const unsigned int* __restrict__ w, int* __restrict__ flag)
{
    const int lane = threadIdx.x;   // 64 threads
    bool ok = true;
#pragma unroll
    for (int i = 0; i < 4; ++i) {
        unsigned x = w[lane * 4 + i];
        unsigned lo = x & 0xffffu, hi = x >> 16;
        ok = ok && (lo <= 0x3F80u) && (hi <= 0x3F80u);
    }
    unsigned long long m = __ballot(ok);
    if (lane == 0) *flag = (m == ~0ULL) ? 1 : 0;
}

// ---------------------------------------------------------------------------
// 256x256-tile, BK=64, 8-wave (2Mx4N), 8-phase deep-pipelined GEMM-BT mainloop
// acc[256x256] = A[256xK] * B[256xK]^T  (bf16 in, fp32 acc)
//
// LDS (128 KiB dynamic): A[buf][half][128][64] at 0, B[...] at elem 32768.
// Chunk swizzle: LDS chunk slot c of row r holds global chunk c^(r&7).
// Schedule per iteration (consumes K-tiles 2i (buf0), 2i+1 (buf1)):
//  ph1: rd buf0 A(q0)+B(n0)   stage A(b1,h0, tile 2i+1)   mfma q(0,0)
//  ph2: rd buf0 B(n1)         stage A(b1,h1, tile 2i+1)   mfma q(0,1)
//  ph3: rd buf0 A(q1)         stage B(b0,h0, tile 2i+2)   mfma q(1,0)
//  ph4:                       stage B(b0,h1, tile 2i+2)   mfma q(1,1)  vmcnt(4)
//  ph5-8: same on buf1; stages A(b0)@2i+2 (ph5,6), B(b1)@2i+3 (ph7,8); vmcnt(4)@8
// vmcnt(4) + barrier => the 8 oldest in-flight loads (one full tile) landed
// before any wave ds_reads them. lgkmcnt(0) before MFMA + end-barrier =>
// all ds_reads of a region drain before any wave's later stage overwrites it.
// ---------------------------------------------------------------------------
#define STAGE_HALF(dstE, gp) do { \
    GLD_LDS((gp) + (size_t)r0 * K + cS,        lds + (dstE) + t * 8); \
    GLD_LDS((gp) + (size_t)(r0 + 64) * K + cS, lds + (dstE) + 4096 + t * 8); } while (0)

#define STG_A(d, h, k0) STAGE_HALF((d)*16384 + (h)*8192, Ag + (size_t)(h)*128*K + (k0))
#define STG_B(d, h, k0) STAGE_HALF(32768 + (d)*16384 + (h)*8192, Bg + (size_t)(h)*128*K + (k0))

#define LDA(af, d, mq) do { _Pragma("unroll") for (int i_ = 0; i_ < 4; ++i_) { \
    const bf16_t* p_ = lds + (d)*16384 + aBase + (((mq)*64) + (i_ << 4) + lrow) * 64; \
    af[i_][0] = *(const bf16x8*)(p_ + so0); \
    af[i_][1] = *(const bf16x8*)(p_ + so1); } } while (0)

#define LDB(bfv, d, nq) do { _Pragma("unroll") for (int j_ = 0; j_ < 2; ++j_) { \
    const bf16_t* p_ = lds + bBase + (d)*16384 + (((nq)*32) + (j_ << 4) + lrow) * 64; \
    bfv[j_][0] = *(const bf16x8*)(p_ + so0); \
    bfv[j_][1] = *(const bf16x8*)(p_ + so1); } } while (0)

#define MFMA_Q(af, bfv, mq, nq) do { _Pragma("unroll") for (int i_ = 0; i_ < 4; ++i_) \
    _Pragma("unroll") for (int j_ = 0; j_ < 2; ++j_) { \
    acc[(mq)*4+i_][(nq)*2+j_] = __builtin_amdgcn_mfma_f32_16x16x32_bf16(af[i_][0], bfv[j_][0], acc[(mq)*4+i_][(nq)*2+j_], 0, 0, 0); \
    acc[(mq)*4+i_][(nq)*2+j_] = __builtin_amdgcn_mfma_f32_16x16x32_bf16(af[i_][1], bfv[j_][1], acc[(mq)*4+i_][(nq)*2+j_], 0, 0, 0); } } while (0)

#define PHASE_SYNC() do { __builtin_amdgcn_s_barrier(); \
    asm volatile("s_waitcnt lgkmcnt(0)" ::: "memory"); \
    __builtin_amdgcn_sched_barrier(0); \
    __builtin_amdgcn_s_setprio(1); } while (0)

#define PHASE_END() do { __builtin_amdgcn_s_setprio(0); \
    __builtin_amdgcn_s_barrier(); } while (0)

#define PHASE_END_VM() do { __builtin_amdgcn_s_setprio(0); \
    asm volatile("s_waitcnt vmcnt(4)" ::: "memory"); \
    __builtin_amdgcn_s_barrier(); } while (0)

__device__ __forceinline__ void gemm256_mainloop(const bf16_t* __restrict__ Ag,
                                                 const bf16_t* __restrict__ Bg,
                                                 const int K, bf16_t* lds,
                                                 f32x4 acc[8][4])
{
    const int t    = threadIdx.x;               // 0..511
    const int wave = t >> 6;
    const int lane = t & 63;
    const int wr   = wave >> 2;                 // 0..1  (M half)
    const int wc   = wave & 3;                  // 0..3  (N quarter)
    const int lrow = lane & 15;
    const int quad = lane >> 4;
    const int g    = lrow & 7;

    // staging mapping: thread t covers row r0(+64), pre-swizzled chunk cS
    const int r0 = t >> 3;
    const int cS = ((t & 7) ^ ((t >> 3) & 7)) << 3;

    // read-side bases (elems)
    const int aBase = wr * 8192;
    const int bBase = 32768 + ((wc >> 1) * 8192) + ((wc & 1) * 4096);
    const int so0 = (quad ^ g) << 3;
    const int so1 = ((4 | quad) ^ g) << 3;

#pragma unroll
    for (int i = 0; i < 8; ++i)
#pragma unroll
        for (int j = 0; j < 4; ++j)
#pragma unroll
            for (int r = 0; r < 4; ++r) acc[i][j][r] = 0.0f;

    // prologue: buf0 <- tile0 (A,B); buf1 <- tile1 (B only; A staged in ph1-2)
    STG_A(0, 0, 0); STG_A(0, 1, 0);
    STG_B(0, 0, 0); STG_B(0, 1, 0);
    STG_B(1, 0, 64); STG_B(1, 1, 64);
    asm volatile("s_waitcnt vmcnt(4)" ::: "memory");   // buf0's 8 loads landed
    __builtin_amdgcn_s_barrier();

    const int NT  = K >> 6;       // K-tiles (even: 8 or 16)
    const int NIT = NT >> 1;

    bf16x8 af0[4][2], af1[4][2], ba[2][2], bb[2][2];

    for (int it = 0; it < NIT; ++it) {
        const int kA1 = (2 * it + 1) << 6;                          // always valid
        const int k2  = ((2 * it + 2) < NT ? (2 * it + 2) : 0) << 6; // clamp keeps vmcnt exact
        const int k3  = ((2 * it + 3) < NT ? (2 * it + 3) : 0) << 6;

        LDA(af0, 0, 0); LDB(ba, 0, 0); STG_A(1, 0, kA1);
        PHASE_SYNC(); MFMA_Q(af0, ba, 0, 0); PHASE_END();

        LDB(bb, 0, 1); STG_A(1, 1, kA1);
        PHASE_SYNC(); MFMA_Q(af0, bb, 0, 1); PHASE_END();

        LDA(af1, 0, 1); STG_B(0, 0, k2);
        PHASE_SYNC(); MFMA_Q(af1, ba, 1, 0); PHASE_END();

        STG_B(0, 1, k2);
        PHASE_SYNC(); MFMA_Q(af1, bb, 1, 1); PHASE_END_VM();

        LDA(af0, 1, 0); LDB(ba, 1, 0); STG_A(0, 0, k2);
        PHASE_SYNC(); MFMA_Q(af0, ba, 0, 0); PHASE_END();

        LDB(bb, 1, 1); STG_A(0, 1, k2);
        PHASE_SYNC(); MFMA_Q(af0, bb, 0, 1); PHASE_END();

        LDA(af1, 1, 1); STG_B(1, 0, k3);
        PHASE_SYNC(); MFMA_Q(af1, ba, 1, 0); PHASE_END();

        STG_B(1, 1, k3);
        PHASE_SYNC(); MFMA_Q(af1, bb, 1, 1); PHASE_END_VM();
    }
    asm volatile("s_waitcnt vmcnt(0)" ::: "memory");   // drain tail stages
}

// ---------------------------------------------------------------------------
// bmm: z[b,n,d] = sum_m adj[b,n,m]*xT[b,d,m] + xadd[b*N+n,d]  (bf16 out)
// grid 256 x 512thr. XCD decode: 4 batches/XCD; paired n-tiles share adj panel.
// ---------------------------------------------------------------------------
__global__ __launch_bounds__(512, 2) void bmm_kernel(const void* __restrict__ adj_in,
                                                     const bf16_t* __restrict__ adj_ws,
                                                     const bf16_t* __restrict__ xT,
                                                     const void* __restrict__ xadd,
                                                     int xadd_bf16,
                                                     const int* __restrict__ flag,
                                                     bf16_t* __restrict__ zout)
{
    extern __shared__ __align__(16) bf16_t lds[];
    const int is_bf = *flag;
    const bf16_t* adj = is_bf ? (const bf16_t*)adj_in : adj_ws;
    const int id   = blockIdx.x;
    const int xcd  = id & 7;
    const int s    = id >> 3;                 // 0..31 per XCD
    const int b    = (xcd << 2) | (s >> 3);   // 4 batches per XCD
    const int tl   = s & 7;
    const int mt   = tl >> 1;                 // 0..3 (rows of 256)
    const int nt2  = tl & 1;                  // 0..1 (cols of 256)
    const bf16_t* Ag = adj + (size_t)b * 1048576 + (size_t)mt * 262144;
    const bf16_t* Bg = xT  + (size_t)b * 524288  + (size_t)nt2 * 262144;
    f32x4 acc[8][4];
    gemm256_mainloop(Ag, Bg, 1024, lds, acc);

    const int lane = threadIdx.x & 63;
    const int wave = threadIdx.x >> 6;
    const int wr = wave >> 2, wc = wave & 3;
    const int lrow = lane & 15, quad = lane >> 4;
    const int xf32 = (!xadd_bf16) && (!is_bf);
    const size_t rowbase = (size_t)b * 1024 + mt * 256 + wr * 128;
    const int colbase = nt2 * 256 + wc * 64;
#pragma unroll
    for (int i = 0; i < 8; ++i)
#pragma unroll
        for (int j = 0; j < 4; ++j)
#pragma unroll
            for (int r = 0; r < 4; ++r) {
                size_t row = rowbase + (i << 4) + (quad << 2) + r;
                int col = colbase + (j << 4) + lrow;
                size_t idx = row * 512 + col;
                float xa = xf32 ? ((const float*)xadd)[idx]
                                : (float)((const bf16_t*)xadd)[idx];
                zout[idx] = (bf16_t)(acc[i][j][r] + xa);
            }
}

// ---------------------------------------------------------------------------
// wgemm: y[n,j] = relu((sum_d z[n,d]*W[j,d] + 2*bias[j]) / (rowsum[n]+1))
// grid 256 x 512thr.
// ---------------------------------------------------------------------------
__global__ __launch_bounds__(512, 2) void wgemm_kernel(const bf16_t* __restrict__ z,
                                                       const bf16_t* __restrict__ W,
                                                       const float* __restrict__ bias,
                                                       const float* __restrict__ rowsum,
                                                       bf16_t* __restrict__ out)
{
    extern __shared__ __align__(16) bf16_t lds[];
    const int id  = blockIdx.x;
    const int xcd = id & 7;
    const int s   = id >> 3;
    const int mt  = (xcd << 4) | (s >> 1);    // 0..127
    const int nt2 = s & 1;
    const bf16_t* Ag = z + (size_t)mt * 131072;
    const bf16_t* Bg = W + (size_t)nt2 * 131072;
    f32x4 acc[8][4];
    gemm256_mainloop(Ag, Bg, 512, lds, acc);

    const int lane = threadIdx.x & 63;
    const int wave = threadIdx.x >> 6;
    const int wr = wave >> 2, wc = wave & 3;
    const int lrow = lane & 15, quad = lane >> 4;
    const int m0 = mt * 256 + wr * 128;
    const int n0 = nt2 * 256 + wc * 64;
    float bi[4];
#pragma unroll
    for (int j = 0; j < 4; ++j) bi[j] = 2.0f * bias[n0 + (j << 4) + lrow];
#pragma unroll
    for (int i = 0; i < 8; ++i)
#pragma unroll
        for (int r = 0; r < 4; ++r) {
            int row = m0 + (i << 4) + (quad << 2) + r;
            float inv_dn = 1.0f / (rowsum[row] + 1.0f);
#pragma unroll
            for (int j = 0; j < 4; ++j) {
                int col = n0 + (j << 4) + lrow;
                float v = fmaxf((acc[i][j][r] + bi[j]) * inv_dn, 0.0f);
                out[(size_t)row * 512 + col] = (bf16_t)v;
            }
        }
}

// ---------------------------------------------------------------------------
// transpose: in[b*N+n, d] -> out[b, d, n] (bf16). grid (16,8,32)
// ---------------------------------------------------------------------------
__global__ __launch_bounds__(256) void transpose_kernel(const void* __restrict__ in,
                                                        bf16_t* __restrict__ out,
                                                        const int* __restrict__ flag,
                                                        int force_bf16)
{
    __shared__ float tile[64][65];
    const int f32 = (!force_bf16) && (*flag == 0);
    const int b  = blockIdx.z;
    const int n0 = blockIdx.x * 64;
    const int d0 = blockIdx.y * 64;
    const int t  = threadIdx.x;
    const size_t base = ((size_t)b * 1024 + n0) * 512 + d0;
#pragma unroll
    for (int pass = 0; pass < 2; ++pass) {
        int r = pass * 32 + (t >> 3);
        int c = (t & 7) << 3;
        size_t off = base + (size_t)r * 512 + c;
        if (f32) {
            const float4* p = (const float4*)((const float*)in + off);
            float4 a = p[0], q = p[1];
            tile[r][c+0]=a.x; tile[r][c+1]=a.y; tile[r][c+2]=a.z; tile[r][c+3]=a.w;
            tile[r][c+4]=q.x; tile[r][c+5]=q.y; tile[r][c+6]=q.z; tile[r][c+7]=q.w;
        } else {
            bf16x8 v = *(const bf16x8*)((const bf16_t*)in + off);
#pragma unroll
            for (int k = 0; k < 8; ++k) tile[r][c + k] = (float)v[k];
        }
    }
    __syncthreads();
    bf16_t* dst = out + ((size_t)b * 512 + d0) * 1024 + n0;
#pragma unroll
    for (int pass = 0; pass < 2; ++pass) {
        int d = pass * 32 + (t >> 3);
        int c = (t & 7) << 3;
        bf16x8 v;
#pragma unroll
        for (int k = 0; k < 8; ++k) v[k] = (bf16_t)tile[c + k][d];
        *(bf16x8*)(dst + (size_t)d * 1024 + c) = v;
    }
}

// ---------------------------------------------------------------------------
// adjrow: rowsum + canonicalize adj->bf16 (store skipped when already bf16).
// ---------------------------------------------------------------------------
__global__ __launch_bounds__(256) void adjrow_kernel(const void* __restrict__ adj,
                                                     const int* __restrict__ flag,
                                                     bf16_t* __restrict__ adj_b,
                                                     float* __restrict__ rowsum)
{
    const int row  = blockIdx.x * 4 + (threadIdx.x >> 6);
    const int lane = threadIdx.x & 63;
    const int f32  = (*flag == 0);
    const size_t base = (size_t)row * 1024 + lane * 16;
    float v[16];
    if (f32) {
        const float4* p = (const float4*)((const float*)adj + base);
#pragma unroll
        for (int i = 0; i < 4; ++i) {
            float4 q = p[i];
            v[i*4+0]=q.x; v[i*4+1]=q.y; v[i*4+2]=q.z; v[i*4+3]=q.w;
        }
    } else {
        const bf16x8* p = (const bf16x8*)((const bf16_t*)adj + base);
        bf16x8 q0 = p[0], q1 = p[1];
#pragma unroll
        for (int k = 0; k < 8; ++k) { v[k] = (float)q0[k]; v[8+k] = (float)q1[k]; }
    }
    float s = 0.0f;
#pragma unroll
    for (int k = 0; k < 16; ++k) s += v[k];
    if (f32) {
        bf16x8 o0, o1;
#pragma unroll
        for (int k = 0; k < 8; ++k) { o0[k] = (bf16_t)v[k]; o1[k] = (bf16_t)v[8+k]; }
        *(bf16x8*)(adj_b + base)     = o0;
        *(bf16x8*)(adj_b + base + 8) = o1;
    }
#pragma unroll
    for (int off = 32; off > 0; off >>= 1) s += __shfl_down(s, off);
    if (lane == 0) rowsum[row] = s;
}

__global__ __launch_bounds__(256) void colsum_kernel(const void* __restrict__ adj_in,
                                                     const bf16_t* __restrict__ adj_ws,
                                                     const int* __restrict__ flag,
                                                     float* __restrict__ colsum)
{
    const bf16_t* a = (*flag) ? (const bf16_t*)adj_in : adj_ws;
    const int b = blockIdx.y;
    const int c = blockIdx.x * 256 + threadIdx.x;
    const int r0 = blockIdx.z * 256;
    const bf16_t* p = a + (size_t)b * 1048576 + (size_t)r0 * 1024 + c;
    float s = 0.0f;
#pragma unroll 8
    for (int r = 0; r < 256; ++r) s += (float)p[(size_t)r * 1024];
    atomicAdd(&colsum[b * 1024 + c], s);
}

__global__ __launch_bounds__(256) void mask_kernel(const float* __restrict__ rowsum,
                                                   const float* __restrict__ colsum,
                                                   void* __restrict__ out,
                                                   const int* __restrict__ flag)
{
    const int i = blockIdx.x * 256 + threadIdx.x;
    float m = (rowsum[i] + colsum[i] == 0.0f) ? 1.0f : 0.0f;
    if (*flag) ((bf16_t*)out)[16777216 + i] = (bf16_t)m;
    else       ((float*)out)[16777216 + i]  = m;
}

// canonicalize W0,W1 -> bf16; biases + ln params -> fp32; zero colsum.
__global__ __launch_bounds__(256) void canon_small(const void* __restrict__ W0,
                                                   const void* __restrict__ W1,
                                                   const void* __restrict__ b0,
                                                   const void* __restrict__ b1,
                                                   const void* __restrict__ g,
                                                   const void* __restrict__ bt,
                                                   const int* __restrict__ flag,
                                                   bf16_t* __restrict__ W0ws,
                                                   bf16_t* __restrict__ W1ws,
                                                   float* __restrict__ par,
                                                   float* __restrict__ colsum)
{
    const int idx = blockIdx.x * 256 + threadIdx.x;
    const int f32 = (*flag == 0);
#define RD(p, i) (f32 ? ((const float*)(p))[i] : (float)((const bf16_t*)(p))[i])
    if      (idx < 262144) W0ws[idx]          = (bf16_t)RD(W0, idx);
    else if (idx < 524288) W1ws[idx - 262144] = (bf16_t)RD(W1, idx - 262144);
    else if (idx < 524800) par[idx - 524288]  = RD(b0, idx - 524288);
    else if (idx < 525312) par[idx - 524288]  = RD(b1, idx - 524800);
    else if (idx < 525824) par[idx - 524288]  = RD(g,  idx - 525312);
    else if (idx < 526336) par[idx - 524288]  = RD(bt, idx - 525824);
    else if (idx < 559104) colsum[idx - 526336] = 0.0f;
#undef RD
}

// ---------------------------------------------------------------------------
// LayerNorm rows of 512 (bf16 in, flagged dtype out). One wave/row.
// ---------------------------------------------------------------------------
__global__ __launch_bounds__(256) void ln_kernel(const bf16_t* __restrict__ x,
                                                 const float* __restrict__ g,
                                                 const float* __restrict__ bb,
                                                 void* __restrict__ out,
                                                 const int* __restrict__ flag)
{
    const int row  = blockIdx.x * 4 + (threadIdx.x >> 6);
    const int lane = threadIdx.x & 63;
    bf16x8 xv = *(const bf16x8*)(x + (size_t)row * 512 + lane * 8);
    float vv[8], s = 0.0f, ss = 0.0f;
#pragma unroll
    for (int k = 0; k < 8; ++k) { vv[k] = (float)xv[k]; s += vv[k]; ss += vv[k] * vv[k]; }
#pragma unroll
    for (int off = 32; off > 0; off >>= 1) { s += __shfl_down(s, off); ss += __shfl_down(ss, off); }
    s = __shfl(s, 0); ss = __shfl(ss, 0);
    const float mu   = s * (1.0f / 512.0f);
    const float var  = ss * (1.0f / 512.0f) - mu * mu;
    const float rstd = rsqrtf(var + 1e-5f);
    float o[8];
#pragma unroll
    for (int k = 0; k < 8; ++k)
        o[k] = (vv[k] - mu) * rstd * g[lane * 8 + k] + bb[lane * 8 + k];
    const size_t obase = (size_t)row * 512 + lane * 8;
    if (*flag) {
        bf16x8 ob;
#pragma unroll
        for (int k = 0; k < 8; ++k) ob[k] = (bf16_t)o[k];
        *(bf16x8*)((bf16_t*)out + obase) = ob;
    } else {
        float4 o0 = {o[0], o[1], o[2], o[3]}, o1 = {o[4], o[5], o[6], o[7]};
        *(float4*)((float*)out + obase)     = o0;
        *(float4*)((float*)out + obase + 4) = o1;
    }
}

// ---------------------------------------------------------------------------
extern "C" void kernel_launch(void* const* d_in, const int* in_sizes, int n_in,
                              void* d_out, int out_size, void* d_ws, size_t ws_size,
                              hipStream_t stream)
{
    const void* adj  = d_in[0];
    const void* x0   = d_in[1];
    const void* W0w  = d_in[3];
    const void* W0b  = d_in[4];
    const void* W1w  = d_in[5];
    const void* W1b  = d_in[6];
    const void* lng  = d_in[7];
    const void* lnb  = d_in[8];

    char* ws = (char*)d_ws;
    bf16_t* adj_ws = (bf16_t*)ws;                   // 64 MiB (fp32-input path only)
    bf16_t* x2     = (bf16_t*)ws;                   // aliases adj_ws after adj dead
    bf16_t* z_buf  = (bf16_t*)(ws + 67108864);
    bf16_t* x1     = (bf16_t*)(ws + 100663296);
    bf16_t* W0ws   = (bf16_t*)(ws + 134217728);
    bf16_t* W1ws   = (bf16_t*)(ws + 134742016);
    float*  par    = (float*)(ws + 135266304);
    float*  rowsum = (float*)(ws + 135274496);
    float*  colsum = (float*)(ws + 135405568);
    int*    flag   = (int*)(ws + 135536640);

    bf16_t* xT = (bf16_t*)d_out;   // d_out head doubles as xT scratch (dead before LN)

    hipFuncSetAttribute((const void*)bmm_kernel,
                        hipFuncAttributeMaxDynamicSharedMemorySize, 131072);
    hipFuncSetAttribute((const void*)wgemm_kernel,
                        hipFuncAttributeMaxDynamicSharedMemorySize, 131072);

    probe_kernel<<<1, 64, 0, stream>>>((const unsigned int*)adj, flag);
    canon_small<<<2184, 256, 0, stream>>>(W0w, W1w, W0b, W1b, lng, lnb, flag,
                                          W0ws, W1ws, par, colsum);
    adjrow_kernel<<<8192, 256, 0, stream>>>(adj, flag, adj_ws, rowsum);
    colsum_kernel<<<dim3(4, 32, 4), 256, 0, stream>>>(adj, adj_ws, flag, colsum);
    mask_kernel<<<128, 256, 0, stream>>>(rowsum, colsum, d_out, flag);

    // layer 1
    transpose_kernel<<<dim3(16, 8, 32), 256, 0, stream>>>(x0, xT, flag, 0);
    bmm_kernel<<<256, 512, 131072, stream>>>(adj, adj_ws, xT, x0, 0, flag, z_buf);
    wgemm_kernel<<<256, 512, 131072, stream>>>(z_buf, W0ws, par, rowsum, x1);

    // layer 2
    transpose_kernel<<<dim3(16, 8, 32), 256, 0, stream>>>(x1, xT, flag, 1);
    bmm_kernel<<<256, 512, 131072, stream>>>(adj, adj_ws, xT, x1, 1, flag, z_buf);
    wgemm_kernel<<<256, 512, 131072, stream>>>(z_buf, W1ws, par + 512, rowsum, x2);

    // final layer norm -> d_out head
    ln_kernel<<<8192, 256, 0, stream>>>(x2, par + 1024, par + 1536, d_out, flag);
}

// Round 4
// 489.005 us; speedup vs baseline: 1.0678x; 1.0079x over previous
//
#include <hip/hip_runtime.h>
#include <stdint.h>

typedef __bf16 bf16_t;
typedef __bf16 bf16x4 __attribute__((ext_vector_type(4)));
typedef __bf16 bf16x8 __attribute__((ext_vector_type(8)));
typedef float  f32x4  __attribute__((ext_vector_type(4)));

#define GLD_LDS(gp, lp) __builtin_amdgcn_global_load_lds( \
    (const __attribute__((address_space(1))) void*)(gp),  \
    (__attribute__((address_space(3))) void*)(lp), 16, 0, 0)

// ---------------------------------------------------------------------------
// dtype probe: flag=1 if inputs are bf16, 0 if fp32.
// ---------------------------------------------------------------------------
__global__ void probe_kernel(const unsigned int* __restrict__ w, int* __restrict__ flag)
{
    const int lane = threadIdx.x;   // 64 threads
    bool ok = true;
#pragma unroll
    for (int i = 0; i < 4; ++i) {
        unsigned x = w[lane * 4 + i];
        unsigned lo = x & 0xffffu, hi = x >> 16;
        ok = ok && (lo <= 0x3F80u) && (hi <= 0x3F80u);
    }
    unsigned long long m = __ballot(ok);
    if (lane == 0) *flag = (m == ~0ULL) ? 1 : 0;
}

// ---------------------------------------------------------------------------
// 256x256-tile, BK=64, 8-wave (2Mx4N), 8-phase deep-pipelined GEMM-BT mainloop
// acc[256x256] = A[256xK] * B[256xK]^T  (bf16 in, fp32 acc)
// (verified round 3: passed, absmax 0.046875)
// ---------------------------------------------------------------------------
#define STAGE_HALF(dstE, gp) do { \
    GLD_LDS((gp) + (size_t)r0 * K + cS,        lds + (dstE) + t * 8); \
    GLD_LDS((gp) + (size_t)(r0 + 64) * K + cS, lds + (dstE) + 4096 + t * 8); } while (0)

#define STG_A(d, h, k0) STAGE_HALF((d)*16384 + (h)*8192, Ag + (size_t)(h)*128*K + (k0))
#define STG_B(d, h, k0) STAGE_HALF(32768 + (d)*16384 + (h)*8192, Bg + (size_t)(h)*128*K + (k0))

#define LDA(af, d, mq) do { _Pragma("unroll") for (int i_ = 0; i_ < 4; ++i_) { \
    const bf16_t* p_ = lds + (d)*16384 + aBase + (((mq)*64) + (i_ << 4) + lrow) * 64; \
    af[i_][0] = *(const bf16x8*)(p_ + so0); \
    af[i_][1] = *(const bf16x8*)(p_ + so1); } } while (0)

#define LDB(bfv, d, nq) do { _Pragma("unroll") for (int j_ = 0; j_ < 2; ++j_) { \
    const bf16_t* p_ = lds + bBase + (d)*16384 + (((nq)*32) + (j_ << 4) + lrow) * 64; \
    bfv[j_][0] = *(const bf16x8*)(p_ + so0); \
    bfv[j_][1] = *(const bf16x8*)(p_ + so1); } } while (0)

#define MFMA_Q(af, bfv, mq, nq) do { _Pragma("unroll") for (int i_ = 0; i_ < 4; ++i_) \
    _Pragma("unroll") for (int j_ = 0; j_ < 2; ++j_) { \
    acc[(mq)*4+i_][(nq)*2+j_] = __builtin_amdgcn_mfma_f32_16x16x32_bf16(af[i_][0], bfv[j_][0], acc[(mq)*4+i_][(nq)*2+j_], 0, 0, 0); \
    acc[(mq)*4+i_][(nq)*2+j_] = __builtin_amdgcn_mfma_f32_16x16x32_bf16(af[i_][1], bfv[j_][1], acc[(mq)*4+i_][(nq)*2+j_], 0, 0, 0); } } while (0)

#define PHASE_SYNC() do { __builtin_amdgcn_s_barrier(); \
    asm volatile("s_waitcnt lgkmcnt(0)" ::: "memory"); \
    __builtin_amdgcn_sched_barrier(0); \
    __builtin_amdgcn_s_setprio(1); } while (0)

#define PHASE_END() do { __builtin_amdgcn_s_setprio(0); \
    __builtin_amdgcn_s_barrier(); } while (0)

#define PHASE_END_VM() do { __builtin_amdgcn_s_setprio(0); \
    asm volatile("s_waitcnt vmcnt(4)" ::: "memory"); \
    __builtin_amdgcn_s_barrier(); } while (0)

__device__ __forceinline__ void gemm256_mainloop(const bf16_t* __restrict__ Ag,
                                                 const bf16_t* __restrict__ Bg,
                                                 const int K, bf16_t* lds,
                                                 f32x4 acc[8][4])
{
    const int t    = threadIdx.x;               // 0..511
    const int wave = t >> 6;
    const int lane = t & 63;
    const int wr   = wave >> 2;                 // 0..1  (M half)
    const int wc   = wave & 3;                  // 0..3  (N quarter)
    const int lrow = lane & 15;
    const int quad = lane >> 4;
    const int g    = lrow & 7;

    const int r0 = t >> 3;
    const int cS = ((t & 7) ^ ((t >> 3) & 7)) << 3;

    const int aBase = wr * 8192;
    const int bBase = 32768 + ((wc >> 1) * 8192) + ((wc & 1) * 4096);
    const int so0 = (quad ^ g) << 3;
    const int so1 = ((4 | quad) ^ g) << 3;

#pragma unroll
    for (int i = 0; i < 8; ++i)
#pragma unroll
        for (int j = 0; j < 4; ++j)
#pragma unroll
            for (int r = 0; r < 4; ++r) acc[i][j][r] = 0.0f;

    STG_A(0, 0, 0); STG_A(0, 1, 0);
    STG_B(0, 0, 0); STG_B(0, 1, 0);
    STG_B(1, 0, 64); STG_B(1, 1, 64);
    asm volatile("s_waitcnt vmcnt(4)" ::: "memory");
    __builtin_amdgcn_s_barrier();

    const int NT  = K >> 6;
    const int NIT = NT >> 1;

    bf16x8 af0[4][2], af1[4][2], ba[2][2], bb[2][2];

    for (int it = 0; it < NIT; ++it) {
        const int kA1 = (2 * it + 1) << 6;
        const int k2  = ((2 * it + 2) < NT ? (2 * it + 2) : 0) << 6;
        const int k3  = ((2 * it + 3) < NT ? (2 * it + 3) : 0) << 6;

        LDA(af0, 0, 0); LDB(ba, 0, 0); STG_A(1, 0, kA1);
        PHASE_SYNC(); MFMA_Q(af0, ba, 0, 0); PHASE_END();

        LDB(bb, 0, 1); STG_A(1, 1, kA1);
        PHASE_SYNC(); MFMA_Q(af0, bb, 0, 1); PHASE_END();

        LDA(af1, 0, 1); STG_B(0, 0, k2);
        PHASE_SYNC(); MFMA_Q(af1, ba, 1, 0); PHASE_END();

        STG_B(0, 1, k2);
        PHASE_SYNC(); MFMA_Q(af1, bb, 1, 1); PHASE_END_VM();

        LDA(af0, 1, 0); LDB(ba, 1, 0); STG_A(0, 0, k2);
        PHASE_SYNC(); MFMA_Q(af0, ba, 0, 0); PHASE_END();

        LDB(bb, 1, 1); STG_A(0, 1, k2);
        PHASE_SYNC(); MFMA_Q(af0, bb, 0, 1); PHASE_END();

        LDA(af1, 1, 1); STG_B(1, 0, k3);
        PHASE_SYNC(); MFMA_Q(af1, ba, 1, 0); PHASE_END();

        STG_B(1, 1, k3);
        PHASE_SYNC(); MFMA_Q(af1, bb, 1, 1); PHASE_END_VM();
    }
    asm volatile("s_waitcnt vmcnt(0)" ::: "memory");
}

// ---------------------------------------------------------------------------
// bmm: z[b,n,d] = sum_m adj[b,n,m]*xT[b,d,m] + xadd[b*N+n,d]  (bf16 out)
// ---------------------------------------------------------------------------
__global__ __launch_bounds__(512, 2) void bmm_kernel(const void* __restrict__ adj_in,
                                                     const bf16_t* __restrict__ adj_ws,
                                                     const bf16_t* __restrict__ xT,
                                                     const void* __restrict__ xadd,
                                                     int xadd_bf16,
                                                     const int* __restrict__ flag,
                                                     bf16_t* __restrict__ zout)
{
    extern __shared__ __align__(16) bf16_t lds[];
    const int is_bf = *flag;
    const bf16_t* adj = is_bf ? (const bf16_t*)adj_in : adj_ws;
    const int id   = blockIdx.x;
    const int xcd  = id & 7;
    const int s    = id >> 3;
    const int b    = (xcd << 2) | (s >> 3);
    const int tl   = s & 7;
    const int mt   = tl >> 1;
    const int nt2  = tl & 1;
    const bf16_t* Ag = adj + (size_t)b * 1048576 + (size_t)mt * 262144;
    const bf16_t* Bg = xT  + (size_t)b * 524288  + (size_t)nt2 * 262144;
    f32x4 acc[8][4];
    gemm256_mainloop(Ag, Bg, 1024, lds, acc);

    const int lane = threadIdx.x & 63;
    const int wave = threadIdx.x >> 6;
    const int wr = wave >> 2, wc = wave & 3;
    const int lrow = lane & 15, quad = lane >> 4;
    const int xf32 = (!xadd_bf16) && (!is_bf);
    const size_t rowbase = (size_t)b * 1024 + mt * 256 + wr * 128;
    const int colbase = nt2 * 256 + wc * 64;
#pragma unroll
    for (int i = 0; i < 8; ++i)
#pragma unroll
        for (int j = 0; j < 4; ++j)
#pragma unroll
            for (int r = 0; r < 4; ++r) {
                size_t row = rowbase + (i << 4) + (quad << 2) + r;
                int col = colbase + (j << 4) + lrow;
                size_t idx = row * 512 + col;
                float xa = xf32 ? ((const float*)xadd)[idx]
                                : (float)((const bf16_t*)xadd)[idx];
                zout[idx] = (bf16_t)(acc[i][j][r] + xa);
            }
}

// ---------------------------------------------------------------------------
// wgemm: y[n,j] = relu((sum_d z[n,d]*W[j,d] + 2*bias[j]) / (rowsum[n]+1))
// Optionally also writes y^T (xTout layout [b][d][n]) straight from registers:
// per fragment, r=0..3 are 4 consecutive n -> one 8B bf16x4 store; the 4 quads
// complete each 32B sector.
// ---------------------------------------------------------------------------
__global__ __launch_bounds__(512, 2) void wgemm_kernel(const bf16_t* __restrict__ z,
                                                       const bf16_t* __restrict__ W,
                                                       const float* __restrict__ bias,
                                                       const float* __restrict__ rowsum,
                                                       bf16_t* __restrict__ out,
                                                       bf16_t* __restrict__ xTout)
{
    extern __shared__ __align__(16) bf16_t lds[];
    const int id  = blockIdx.x;
    const int xcd = id & 7;
    const int s   = id >> 3;
    const int mt  = (xcd << 4) | (s >> 1);    // 0..127
    const int nt2 = s & 1;
    const bf16_t* Ag = z + (size_t)mt * 131072;
    const bf16_t* Bg = W + (size_t)nt2 * 131072;
    f32x4 acc[8][4];
    gemm256_mainloop(Ag, Bg, 512, lds, acc);

    const int lane = threadIdx.x & 63;
    const int wave = threadIdx.x >> 6;
    const int wr = wave >> 2, wc = wave & 3;
    const int lrow = lane & 15, quad = lane >> 4;
    const int m0 = mt * 256 + wr * 128;
    const int n0 = nt2 * 256 + wc * 64;
    bf16_t* xtb = xTout ? (xTout + (size_t)(mt >> 2) * 524288) : (bf16_t*)0;
    float bi[4];
#pragma unroll
    for (int j = 0; j < 4; ++j) bi[j] = 2.0f * bias[n0 + (j << 4) + lrow];
#pragma unroll
    for (int i = 0; i < 8; ++i) {
        const int rowb = m0 + (i << 4) + (quad << 2);
        float invd[4];
#pragma unroll
        for (int r = 0; r < 4; ++r) invd[r] = 1.0f / (rowsum[rowb + r] + 1.0f);
#pragma unroll
        for (int j = 0; j < 4; ++j) {
            const int col = n0 + (j << 4) + lrow;
            bf16x4 tv;
#pragma unroll
            for (int r = 0; r < 4; ++r) {
                float v = fmaxf((acc[i][j][r] + bi[j]) * invd[r], 0.0f);
                bf16_t bv = (bf16_t)v;
                out[(size_t)(rowb + r) * 512 + col] = bv;
                tv[r] = bv;
            }
            if (xtb) *(bf16x4*)(xtb + (size_t)col * 1024 + (rowb & 1023)) = tv;
        }
    }
}

// ---------------------------------------------------------------------------
// transpose: in[b*N+n, d] -> out[b, d, n] (bf16). grid (16,8,32)
// (layer-1 input only; layer-2 transpose is fused into wgemm's epilogue)
// ---------------------------------------------------------------------------
__global__ __launch_bounds__(256) void transpose_kernel(const void* __restrict__ in,
                                                        bf16_t* __restrict__ out,
                                                        const int* __restrict__ flag,
                                                        int force_bf16)
{
    __shared__ float tile[64][65];
    const int f32 = (!force_bf16) && (*flag == 0);
    const int b  = blockIdx.z;
    const int n0 = blockIdx.x * 64;
    const int d0 = blockIdx.y * 64;
    const int t  = threadIdx.x;
    const size_t base = ((size_t)b * 1024 + n0) * 512 + d0;
#pragma unroll
    for (int pass = 0; pass < 2; ++pass) {
        int r = pass * 32 + (t >> 3);
        int c = (t & 7) << 3;
        size_t off = base + (size_t)r * 512 + c;
        if (f32) {
            const float4* p = (const float4*)((const float*)in + off);
            float4 a = p[0], q = p[1];
            tile[r][c+0]=a.x; tile[r][c+1]=a.y; tile[r][c+2]=a.z; tile[r][c+3]=a.w;
            tile[r][c+4]=q.x; tile[r][c+5]=q.y; tile[r][c+6]=q.z; tile[r][c+7]=q.w;
        } else {
            bf16x8 v = *(const bf16x8*)((const bf16_t*)in + off);
#pragma unroll
            for (int k = 0; k < 8; ++k) tile[r][c + k] = (float)v[k];
        }
    }
    __syncthreads();
    bf16_t* dst = out + ((size_t)b * 512 + d0) * 1024 + n0;
#pragma unroll
    for (int pass = 0; pass < 2; ++pass) {
        int d = pass * 32 + (t >> 3);
        int c = (t & 7) << 3;
        bf16x8 v;
#pragma unroll
        for (int k = 0; k < 8; ++k) v[k] = (bf16_t)tile[c + k][d];
        *(bf16x8*)(dst + (size_t)d * 1024 + c) = v;
    }
}

// ---------------------------------------------------------------------------
// adjrow: one pass over adj -> rowsum + colsum + bf16 canonicalized copy.
// grid 512 x 256thr; block = 64 rows; wave owns a 256-col quarter.
// ---------------------------------------------------------------------------
__global__ __launch_bounds__(256) void adjrow_kernel(const void* __restrict__ adj,
                                                     const int* __restrict__ flag,
                                                     bf16_t* __restrict__ adj_b,
                                                     float* __restrict__ rowsum,
                                                     float* __restrict__ colsum)
{
    __shared__ float rpart[64][4];
    const int f32  = (*flag == 0);
    const int wave = threadIdx.x >> 6;
    const int lane = threadIdx.x & 63;
    const int r0   = blockIdx.x * 64;
    const int c    = wave * 256 + lane * 4;
    float ca0 = 0.0f, ca1 = 0.0f, ca2 = 0.0f, ca3 = 0.0f;
    for (int r = 0; r < 64; ++r) {
        const size_t base = (size_t)(r0 + r) * 1024 + c;
        float v0, v1, v2, v3;
        if (f32) {
            float4 q = *(const float4*)((const float*)adj + base);
            v0 = q.x; v1 = q.y; v2 = q.z; v3 = q.w;
            bf16x4 o = { (bf16_t)v0, (bf16_t)v1, (bf16_t)v2, (bf16_t)v3 };
            *(bf16x4*)(adj_b + base) = o;
        } else {
            bf16x4 q = *(const bf16x4*)((const bf16_t*)adj + base);
            v0 = (float)q[0]; v1 = (float)q[1]; v2 = (float)q[2]; v3 = (float)q[3];
        }
        ca0 += v0; ca1 += v1; ca2 += v2; ca3 += v3;
        float sr = (v0 + v1) + (v2 + v3);
#pragma unroll
        for (int off = 32; off > 0; off >>= 1) sr += __shfl_down(sr, off);
        if (lane == 0) rpart[r][wave] = sr;
    }
    __syncthreads();
    if (threadIdx.x < 64) {
        const int r = threadIdx.x;
        rowsum[r0 + r] = (rpart[r][0] + rpart[r][1]) + (rpart[r][2] + rpart[r][3]);
    }
    float* cb = colsum + (size_t)(r0 >> 10) * 1024 + c;
    atomicAdd(cb + 0, ca0);
    atomicAdd(cb + 1, ca1);
    atomicAdd(cb + 2, ca2);
    atomicAdd(cb + 3, ca3);
}

__global__ __launch_bounds__(256) void mask_kernel(const float* __restrict__ rowsum,
                                                   const float* __restrict__ colsum,
                                                   void* __restrict__ out,
                                                   const int* __restrict__ flag)
{
    const int i = blockIdx.x * 256 + threadIdx.x;
    float m = (rowsum[i] + colsum[i] == 0.0f) ? 1.0f : 0.0f;
    if (*flag) ((bf16_t*)out)[16777216 + i] = (bf16_t)m;
    else       ((float*)out)[16777216 + i]  = m;
}

// canonicalize W0,W1 -> bf16; biases + ln params -> fp32; zero colsum.
__global__ __launch_bounds__(256) void canon_small(const void* __restrict__ W0,
                                                   const void* __restrict__ W1,
                                                   const void* __restrict__ b0,
                                                   const void* __restrict__ b1,
                                                   const void* __restrict__ g,
                                                   const void* __restrict__ bt,
                                                   const int* __restrict__ flag,
                                                   bf16_t* __restrict__ W0ws,
                                                   bf16_t* __restrict__ W1ws,
                                                   float* __restrict__ par,
                                                   float* __restrict__ colsum)
{
    const int idx = blockIdx.x * 256 + threadIdx.x;
    const int f32 = (*flag == 0);
#define RD(p, i) (f32 ? ((const float*)(p))[i] : (float)((const bf16_t*)(p))[i])
    if      (idx < 262144) W0ws[idx]          = (bf16_t)RD(W0, idx);
    else if (idx < 524288) W1ws[idx - 262144] = (bf16_t)RD(W1, idx - 262144);
    else if (idx < 524800) par[idx - 524288]  = RD(b0, idx - 524288);
    else if (idx < 525312) par[idx - 524288]  = RD(b1, idx - 524800);
    else if (idx < 525824) par[idx - 524288]  = RD(g,  idx - 525312);
    else if (idx < 526336) par[idx - 524288]  = RD(bt, idx - 525824);
    else if (idx < 559104) colsum[idx - 526336] = 0.0f;
#undef RD
}

// ---------------------------------------------------------------------------
// LayerNorm rows of 512 (bf16 in, flagged dtype out). One wave/row.
// ---------------------------------------------------------------------------
__global__ __launch_bounds__(256) void ln_kernel(const bf16_t* __restrict__ x,
                                                 const float* __restrict__ g,
                                                 const float* __restrict__ bb,
                                                 void* __restrict__ out,
                                                 const int* __restrict__ flag)
{
    const int row  = blockIdx.x * 4 + (threadIdx.x >> 6);
    const int lane = threadIdx.x & 63;
    bf16x8 xv = *(const bf16x8*)(x + (size_t)row * 512 + lane * 8);
    float vv[8], s = 0.0f, ss = 0.0f;
#pragma unroll
    for (int k = 0; k < 8; ++k) { vv[k] = (float)xv[k]; s += vv[k]; ss += vv[k] * vv[k]; }
#pragma unroll
    for (int off = 32; off > 0; off >>= 1) { s += __shfl_down(s, off); ss += __shfl_down(ss, off); }
    s = __shfl(s, 0); ss = __shfl(ss, 0);
    const float mu   = s * (1.0f / 512.0f);
    const float var  = ss * (1.0f / 512.0f) - mu * mu;
    const float rstd = rsqrtf(var + 1e-5f);
    float o[8];
#pragma unroll
    for (int k = 0; k < 8; ++k)
        o[k] = (vv[k] - mu) * rstd * g[lane * 8 + k] + bb[lane * 8 + k];
    const size_t obase = (size_t)row * 512 + lane * 8;
    if (*flag) {
        bf16x8 ob;
#pragma unroll
        for (int k = 0; k < 8; ++k) ob[k] = (bf16_t)o[k];
        *(bf16x8*)((bf16_t*)out + obase) = ob;
    } else {
        float4 o0 = {o[0], o[1], o[2], o[3]}, o1 = {o[4], o[5], o[6], o[7]};
        *(float4*)((float*)out + obase)     = o0;
        *(float4*)((float*)out + obase + 4) = o1;
    }
}

// ---------------------------------------------------------------------------
extern "C" void kernel_launch(void* const* d_in, const int* in_sizes, int n_in,
                              void* d_out, int out_size, void* d_ws, size_t ws_size,
                              hipStream_t stream)
{
    const void* adj  = d_in[0];
    const void* x0   = d_in[1];
    const void* W0w  = d_in[3];
    const void* W0b  = d_in[4];
    const void* W1w  = d_in[5];
    const void* W1b  = d_in[6];
    const void* lng  = d_in[7];
    const void* lnb  = d_in[8];

    char* ws = (char*)d_ws;
    bf16_t* adj_ws = (bf16_t*)ws;                   // 64 MiB (fp32-input path only)
    bf16_t* x2     = (bf16_t*)ws;                   // aliases adj_ws after adj dead
    bf16_t* z_buf  = (bf16_t*)(ws + 67108864);
    bf16_t* x1     = (bf16_t*)(ws + 100663296);
    bf16_t* W0ws   = (bf16_t*)(ws + 134217728);
    bf16_t* W1ws   = (bf16_t*)(ws + 134742016);
    float*  par    = (float*)(ws + 135266304);
    float*  rowsum = (float*)(ws + 135274496);
    float*  colsum = (float*)(ws + 135405568);
    int*    flag   = (int*)(ws + 135536640);

    bf16_t* xT = (bf16_t*)d_out;   // d_out head doubles as xT scratch (dead before LN)

    hipFuncSetAttribute((const void*)bmm_kernel,
                        hipFuncAttributeMaxDynamicSharedMemorySize, 131072);
    hipFuncSetAttribute((const void*)wgemm_kernel,
                        hipFuncAttributeMaxDynamicSharedMemorySize, 131072);

    probe_kernel<<<1, 64, 0, stream>>>((const unsigned int*)adj, flag);
    canon_small<<<2184, 256, 0, stream>>>(W0w, W1w, W0b, W1b, lng, lnb, flag,
                                          W0ws, W1ws, par, colsum);
    adjrow_kernel<<<512, 256, 0, stream>>>(adj, flag, adj_ws, rowsum, colsum);
    mask_kernel<<<128, 256, 0, stream>>>(rowsum, colsum, d_out, flag);

    // layer 1
    transpose_kernel<<<dim3(16, 8, 32), 256, 0, stream>>>(x0, xT, flag, 0);
    bmm_kernel<<<256, 512, 131072, stream>>>(adj, adj_ws, xT, x0, 0, flag, z_buf);
    wgemm_kernel<<<256, 512, 131072, stream>>>(z_buf, W0ws, par, rowsum, x1, xT);

    // layer 2 (xT written by wgemm1's fused transpose)
    bmm_kernel<<<256, 512, 131072, stream>>>(adj, adj_ws, xT, x1, 1, flag, z_buf);
    wgemm_kernel<<<256, 512, 131072, stream>>>(z_buf, W1ws, par + 512, rowsum, x2,
                                               (bf16_t*)0);

    // final layer norm -> d_out head
    ln_kernel<<<8192, 256, 0, stream>>>(x2, par + 1024, par + 1536, d_out, flag);
}